// Round 1
// baseline (1646.296 us; speedup 1.0000x reference)
//
#include <hip/hip_runtime.h>

namespace {

constexpr int kHW  = 128 * 128;
constexpr int kCH  = 256;
constexpr int kHID = 10;
constexpr int kB   = 8;

__device__ __forceinline__ float sigm(float x) {
    return __builtin_amdgcn_rcpf(1.0f + __expf(-x));
}
__device__ __forceinline__ float tanh_(float x) {
    return 1.0f - 2.0f * __builtin_amdgcn_rcpf(__expf(2.0f * x) + 1.0f);
}

// ---------------- Kernel 1: six leaf ConvLSTM cells ----------------
// one thread = 2 adjacent pixels (float2); 6 leaves sequentially.
// writes out slices 0..5 (half_h) and 9..14 (half_c)
__global__ __launch_bounds__(256) void k_leaf(
    const float* __restrict__ p_fea,   // [B, CH, HW]
    const float* __restrict__ seg_p,   // [B, 7, HW]
    const float* __restrict__ W_leaf,  // [6, 30, 257]
    float* __restrict__ out)           // [18, B, 10, HW]
{
    const int t  = blockIdx.x * 256 + threadIdx.x;   // 0 .. B*HW/2-1
    const int b  = t >> 13;                          // / (HW/2)
    const int hw = (t & (kHW / 2 - 1)) * 2;
    const float2* pf = reinterpret_cast<const float2*>(p_fea + b * kCH * kHW + hw);

    for (int n = 0; n < 6; ++n) {
        const float* W = W_leaf + n * 30 * 257;
        float acc0[30], acc1[30];
        #pragma unroll
        for (int o = 0; o < 30; ++o) { acc0[o] = 0.f; acc1[o] = 0.f; }

        float2 xa[8], xb[8];
        #pragma unroll
        for (int j = 0; j < 8; ++j) xa[j] = pf[j * (kHW / 2)];

        #pragma unroll 1
        for (int c0 = 0; c0 < kCH; c0 += 16) {
            #pragma unroll
            for (int j = 0; j < 8; ++j) xb[j] = pf[(c0 + 8 + j) * (kHW / 2)];
            #pragma unroll
            for (int o = 0; o < 30; ++o) {
                float a0 = acc0[o], a1 = acc1[o];
                #pragma unroll
                for (int j = 0; j < 8; ++j) {
                    const float w = W[o * 257 + c0 + j];
                    a0 = fmaf(w, xa[j].x, a0);
                    a1 = fmaf(w, xa[j].y, a1);
                }
                acc0[o] = a0; acc1[o] = a1;
            }
            if (c0 + 16 < kCH) {
                #pragma unroll
                for (int j = 0; j < 8; ++j) xa[j] = pf[(c0 + 16 + j) * (kHW / 2)];
            }
            #pragma unroll
            for (int o = 0; o < 30; ++o) {
                float a0 = acc0[o], a1 = acc1[o];
                #pragma unroll
                for (int j = 0; j < 8; ++j) {
                    const float w = W[o * 257 + c0 + 8 + j];
                    a0 = fmaf(w, xb[j].x, a0);
                    a1 = fmaf(w, xb[j].y, a1);
                }
                acc0[o] = a0; acc1[o] = a1;
            }
        }

        const float2 seg = *reinterpret_cast<const float2*>(
            seg_p + (b * 7 + (n + 1)) * kHW + hw);
        #pragma unroll
        for (int o = 0; o < 30; ++o) {
            const float w = W[o * 257 + 256];
            acc0[o] = fmaf(w, seg.x, acc0[o]);
            acc1[o] = fmaf(w, seg.y, acc1[o]);
        }

        // gates: i = rows 0..9, o = 10..19, g = 20..29
        #pragma unroll
        for (int q = 0; q < 10; ++q) {
            const float cn0 = sigm(acc0[q]) * tanh_(acc0[20 + q]);
            const float cn1 = sigm(acc1[q]) * tanh_(acc1[20 + q]);
            const float hn0 = sigm(acc0[10 + q]) * tanh_(cn0);
            const float hn1 = sigm(acc1[10 + q]) * tanh_(cn1);
            *reinterpret_cast<float2*>(out + ((n * kB + b) * kHID + q) * kHW + hw) =
                make_float2(hn0, hn1);
            *reinterpret_cast<float2*>(out + (((9 + n) * kB + b) * kHID + q) * kHW + hw) =
                make_float2(cn0, cn1);
        }
    }
}

// 10-row x 8-channel accumulate helper (weights have row stride `rs`)
#define ACC8(accArr, Wbase, rs, rowoff)                                          \
    _Pragma("unroll")                                                            \
    for (int q = 0; q < 10; ++q) {                                               \
        float a_ = accArr[q];                                                    \
        _Pragma("unroll")                                                        \
        for (int j = 0; j < 8; ++j)                                              \
            a_ = fmaf((Wbase)[((rowoff) + q) * (rs) + cbase + j], xcur[j], a_);  \
        accArr[q] = a_;                                                          \
    }

// ---------------- Kernel 2: up + low tree cells ----------------
// reads half_h (slices 0..5) / half_c (9..14); writes low_h (6,7), up_c (15), low_c (16)
// up_h is never used downstream -> skip W_up's o-gate rows entirely.
__global__ __launch_bounds__(256) void k_uplow(
    const float* __restrict__ h_fea,   // [B, CH, HW]
    const float* __restrict__ seg_h,   // [B, 3, HW]
    const float* __restrict__ W_up,    // [30, 267]
    const float* __restrict__ Wf_up,   // [10, 267]
    const float* __restrict__ W_low,   // [30, 267]
    const float* __restrict__ Wf_low,  // [10, 267]
    float* __restrict__ out)
{
    const int t  = blockIdx.x * 256 + threadIdx.x;   // 0 .. B*HW-1
    const int b  = t >> 14;
    const int hw = t & (kHW - 1);
    const float* hf = h_fea + b * kCH * kHW + hw;

    float aUi[10], aUg[10], fU[10];
    float aLi[10], aLo[10], aLg[10], fL[10];
    #pragma unroll
    for (int q = 0; q < 10; ++q) {
        aUi[q] = aUg[q] = fU[q] = 0.f;
        aLi[q] = aLo[q] = aLg[q] = fL[q] = 0.f;
    }

    float xa8[8], xb8[8];
    #pragma unroll
    for (int j = 0; j < 8; ++j) xa8[j] = hf[j * kHW];

    #pragma unroll 1
    for (int c0 = 0; c0 < kCH; c0 += 16) {
        #pragma unroll
        for (int j = 0; j < 8; ++j) xb8[j] = hf[(c0 + 8 + j) * kHW];
        {
            const float* xcur = xa8; const int cbase = c0;
            ACC8(aUi, W_up, 267, 0)  ACC8(aUg, W_up, 267, 20)  ACC8(fU, Wf_up, 267, 0)
            ACC8(aLi, W_low, 267, 0) ACC8(aLo, W_low, 267, 10) ACC8(aLg, W_low, 267, 20)
            ACC8(fL, Wf_low, 267, 0)
        }
        if (c0 + 16 < kCH) {
            #pragma unroll
            for (int j = 0; j < 8; ++j) xa8[j] = hf[(c0 + 16 + j) * kHW];
        }
        {
            const float* xcur = xb8; const int cbase = c0 + 8;
            ACC8(aUi, W_up, 267, 0)  ACC8(aUg, W_up, 267, 20)  ACC8(fU, Wf_up, 267, 0)
            ACC8(aLi, W_low, 267, 0) ACC8(aLo, W_low, 267, 10) ACC8(aLg, W_low, 267, 20)
            ACC8(fL, Wf_low, 267, 0)
        }
    }

    // seg channel (col 256): up uses seg_h[:,1], low uses seg_h[:,2]
    const float sU = seg_h[(b * 3 + 1) * kHW + hw];
    const float sL = seg_h[(b * 3 + 2) * kHW + hw];
    #pragma unroll
    for (int q = 0; q < 10; ++q) {
        aUi[q] = fmaf(W_up[q * 267 + 256], sU, aUi[q]);
        aUg[q] = fmaf(W_up[(20 + q) * 267 + 256], sU, aUg[q]);
        fU[q]  = fmaf(Wf_up[q * 267 + 256], sU, fU[q]);
        aLi[q] = fmaf(W_low[q * 267 + 256], sL, aLi[q]);
        aLo[q] = fmaf(W_low[(10 + q) * 267 + 256], sL, aLo[q]);
        aLg[q] = fmaf(W_low[(20 + q) * 267 + 256], sL, aLg[q]);
        fL[q]  = fmaf(Wf_low[q * 267 + 256], sL, fL[q]);
    }

    // children: up = leaves 0..3, low = leaves 4..5
    float hsU[10], csU[10], hsL[10], csL[10];
    #pragma unroll
    for (int q = 0; q < 10; ++q) { hsU[q] = csU[q] = hsL[q] = csL[q] = 0.f; }

    #pragma unroll 1
    for (int n = 0; n < 4; ++n) {
        float hc[10], cv[10];
        #pragma unroll
        for (int q = 0; q < 10; ++q) hc[q] = out[((n * kB + b) * kHID + q) * kHW + hw];
        #pragma unroll
        for (int q = 0; q < 10; ++q) cv[q] = out[(((9 + n) * kB + b) * kHID + q) * kHW + hw];
        #pragma unroll
        for (int q = 0; q < 10; ++q) hsU[q] += hc[q];
        #pragma unroll
        for (int q = 0; q < 10; ++q) {
            float fh = fU[q];
            #pragma unroll
            for (int j = 0; j < 10; ++j) fh = fmaf(Wf_up[q * 267 + 257 + j], hc[j], fh);
            csU[q] = fmaf(sigm(fh), cv[q], csU[q]);
        }
    }
    #pragma unroll 1
    for (int n = 4; n < 6; ++n) {
        float hc[10], cv[10];
        #pragma unroll
        for (int q = 0; q < 10; ++q) hc[q] = out[((n * kB + b) * kHID + q) * kHW + hw];
        #pragma unroll
        for (int q = 0; q < 10; ++q) cv[q] = out[(((9 + n) * kB + b) * kHID + q) * kHW + hw];
        #pragma unroll
        for (int q = 0; q < 10; ++q) hsL[q] += hc[q];
        #pragma unroll
        for (int q = 0; q < 10; ++q) {
            float fh = fL[q];
            #pragma unroll
            for (int j = 0; j < 10; ++j) fh = fmaf(Wf_low[q * 267 + 257 + j], hc[j], fh);
            csL[q] = fmaf(sigm(fh), cv[q], csL[q]);
        }
    }

    // hidden-sum contributions (cols 257..266)
    #pragma unroll
    for (int q = 0; q < 10; ++q) {
        float ai = aUi[q], ag = aUg[q];
        #pragma unroll
        for (int j = 0; j < 10; ++j) {
            ai = fmaf(W_up[q * 267 + 257 + j], hsU[j], ai);
            ag = fmaf(W_up[(20 + q) * 267 + 257 + j], hsU[j], ag);
        }
        aUi[q] = ai; aUg[q] = ag;
    }
    #pragma unroll
    for (int q = 0; q < 10; ++q) {
        float ai = aLi[q], ao = aLo[q], ag = aLg[q];
        #pragma unroll
        for (int j = 0; j < 10; ++j) {
            ai = fmaf(W_low[q * 267 + 257 + j], hsL[j], ai);
            ao = fmaf(W_low[(10 + q) * 267 + 257 + j], hsL[j], ao);
            ag = fmaf(W_low[(20 + q) * 267 + 257 + j], hsL[j], ag);
        }
        aLi[q] = ai; aLo[q] = ao; aLg[q] = ag;
    }

    // up cell: only c is needed downstream / in output (slice 15)
    #pragma unroll
    for (int q = 0; q < 10; ++q) {
        out[((15 * kB + b) * kHID + q) * kHW + hw] =
            sigm(aUi[q]) * tanh_(aUg[q]) + csU[q];
    }
    // low cell: h (slices 6 and 7) and c (slice 16)
    #pragma unroll
    for (int q = 0; q < 10; ++q) {
        const float lcv = sigm(aLi[q]) * tanh_(aLg[q]) + csL[q];
        const float lhv = sigm(aLo[q]) * tanh_(lcv);
        out[((6 * kB + b) * kHID + q) * kHW + hw]  = lhv;
        out[((7 * kB + b) * kHID + q) * kHW + hw]  = lhv;
        out[((16 * kB + b) * kHID + q) * kHW + hw] = lcv;
    }
}

// ---------------- Kernel 3: full body cell ----------------
// reads low_h (6), up_c (15), low_c (16); writes full_h (8), full_c (17)
__global__ __launch_bounds__(256) void k_full(
    const float* __restrict__ f_fea,    // [B, CH, HW]
    const float* __restrict__ seg_f,    // [B, 2, HW]
    const float* __restrict__ W_full,   // [30, 267]
    const float* __restrict__ Wf_full,  // [10, 267]
    float* __restrict__ out)
{
    const int t  = blockIdx.x * 256 + threadIdx.x;
    const int b  = t >> 14;
    const int hw = t & (kHW - 1);
    const float* ff = f_fea + b * kCH * kHW + hw;

    float ai[10], ao[10], ag[10], fx[10];
    #pragma unroll
    for (int q = 0; q < 10; ++q) { ai[q] = ao[q] = ag[q] = fx[q] = 0.f; }

    float xa8[8], xb8[8];
    #pragma unroll
    for (int j = 0; j < 8; ++j) xa8[j] = ff[j * kHW];

    #pragma unroll 1
    for (int c0 = 0; c0 < kCH; c0 += 16) {
        #pragma unroll
        for (int j = 0; j < 8; ++j) xb8[j] = ff[(c0 + 8 + j) * kHW];
        {
            const float* xcur = xa8; const int cbase = c0;
            ACC8(ai, W_full, 267, 0) ACC8(ao, W_full, 267, 10)
            ACC8(ag, W_full, 267, 20) ACC8(fx, Wf_full, 267, 0)
        }
        if (c0 + 16 < kCH) {
            #pragma unroll
            for (int j = 0; j < 8; ++j) xa8[j] = ff[(c0 + 16 + j) * kHW];
        }
        {
            const float* xcur = xb8; const int cbase = c0 + 8;
            ACC8(ai, W_full, 267, 0) ACC8(ao, W_full, 267, 10)
            ACC8(ag, W_full, 267, 20) ACC8(fx, Wf_full, 267, 0)
        }
    }

    const float sF = seg_f[(b * 2 + 1) * kHW + hw];
    #pragma unroll
    for (int q = 0; q < 10; ++q) {
        ai[q] = fmaf(W_full[q * 267 + 256], sF, ai[q]);
        ao[q] = fmaf(W_full[(10 + q) * 267 + 256], sF, ao[q]);
        ag[q] = fmaf(W_full[(20 + q) * 267 + 256], sF, ag[q]);
        fx[q] = fmaf(Wf_full[q * 267 + 256], sF, fx[q]);
    }

    float lh[10], uc[10], lc[10];
    #pragma unroll
    for (int q = 0; q < 10; ++q) lh[q] = out[((6 * kB + b) * kHID + q) * kHW + hw];
    #pragma unroll
    for (int q = 0; q < 10; ++q) uc[q] = out[((15 * kB + b) * kHID + q) * kHW + hw];
    #pragma unroll
    for (int q = 0; q < 10; ++q) lc[q] = out[((16 * kB + b) * kHID + q) * kHW + hw];

    // h_ch = [low_h, low_h] -> h_sum = 2*low_h; both children share f
    #pragma unroll
    for (int q = 0; q < 10; ++q) {
        float a0 = ai[q], a1 = ao[q], a2 = ag[q], fh = fx[q];
        #pragma unroll
        for (int j = 0; j < 10; ++j) {
            const float h2 = 2.0f * lh[j];
            a0 = fmaf(W_full[q * 267 + 257 + j], h2, a0);
            a1 = fmaf(W_full[(10 + q) * 267 + 257 + j], h2, a1);
            a2 = fmaf(W_full[(20 + q) * 267 + 257 + j], h2, a2);
            fh = fmaf(Wf_full[q * 267 + 257 + j], lh[j], fh);
        }
        const float f  = sigm(fh);
        const float cf = sigm(a0) * tanh_(a2) + f * (uc[q] + lc[q]);
        const float hv = sigm(a1) * tanh_(cf);
        out[((8 * kB + b) * kHID + q) * kHW + hw]  = hv;
        out[((17 * kB + b) * kHID + q) * kHW + hw] = cf;
    }
}

}  // namespace

extern "C" void kernel_launch(void* const* d_in, const int* in_sizes, int n_in,
                              void* d_out, int out_size, void* d_ws, size_t ws_size,
                              hipStream_t stream) {
    const float* seg_p   = (const float*)d_in[0];
    const float* seg_h   = (const float*)d_in[1];
    const float* seg_f   = (const float*)d_in[2];
    const float* p_fea   = (const float*)d_in[3];
    const float* h_fea   = (const float*)d_in[4];
    const float* f_fea   = (const float*)d_in[5];
    const float* W_leaf  = (const float*)d_in[6];
    const float* W_up    = (const float*)d_in[7];
    const float* Wf_up   = (const float*)d_in[8];
    const float* W_low   = (const float*)d_in[9];
    const float* Wf_low  = (const float*)d_in[10];
    const float* W_full  = (const float*)d_in[11];
    const float* Wf_full = (const float*)d_in[12];
    float* out = (float*)d_out;

    hipLaunchKernelGGL(k_leaf, dim3(kB * kHW / 2 / 256), dim3(256), 0, stream,
                       p_fea, seg_p, W_leaf, out);
    hipLaunchKernelGGL(k_uplow, dim3(kB * kHW / 256), dim3(256), 0, stream,
                       h_fea, seg_h, W_up, Wf_up, W_low, Wf_low, out);
    hipLaunchKernelGGL(k_full, dim3(kB * kHW / 256), dim3(256), 0, stream,
                       f_fea, seg_f, W_full, Wf_full, out);
}

// Round 2
// 1018.301 us; speedup vs baseline: 1.6167x; 1.6167x over previous
//
#include <hip/hip_runtime.h>

namespace {

constexpr int kHW  = 128 * 128;
constexpr int kCH  = 256;
constexpr int kHID = 10;
constexpr int kB   = 8;

typedef __attribute__((ext_vector_type(8))) short bf16x8;
typedef __attribute__((ext_vector_type(4))) float f32x4;

constexpr int kMT      = 15;          // M-tiles of 16 rows (180 real rows -> 60 triples *4 = 240)
constexpr int kSegOff  = 240 * 512;   // byte offset of seg-weight table in LDS
constexpr int kLdsBytes = kSegOff + 60 * 4 * 4;

__device__ __forceinline__ float sigm(float x) {
    return __builtin_amdgcn_rcpf(1.0f + __expf(-x));
}
__device__ __forceinline__ float tanh_(float x) {
    return 1.0f - 2.0f * __builtin_amdgcn_rcpf(__expf(2.0f * x) + 1.0f);
}
__device__ __forceinline__ unsigned short bf16b(float f) {
    unsigned u = __float_as_uint(f);
    return (unsigned short)((u + 0x7FFFu + ((u >> 16) & 1u)) >> 16);  // RNE-ish
}
__device__ __forceinline__ bf16x8 load_bfrag(const float* __restrict__ base) {
    float v[8];
    #pragma unroll
    for (int j = 0; j < 8; ++j) v[j] = base[j * kHW];
    bf16x8 r;
    #pragma unroll
    for (int j = 0; j < 8; ++j) r[j] = (short)bf16b(v[j]);
    return r;
}

// ---------------- Kernel 1 (MFMA): six leaf ConvLSTM cells ----------------
// GEMM: Wp[240,256](bf16, LDS, swizzled) x X[256, px](p_fea fp32->bf16).
// Row permutation: triple t = leaf*10+q, rows t*4+{0:i,1:g,2:o,3:pad}.
// C-layout (m89): col=lane&15, row=(lane>>4)*4+reg -> lane's 4 regs = one triple.
__global__ __launch_bounds__(256, 1) void k_leaf_mfma(
    const float* __restrict__ p_fea,   // [B, CH, HW]
    const float* __restrict__ seg_p,   // [B, 7, HW]
    const float* __restrict__ W_leaf,  // [6, 30, 257]
    float* __restrict__ out)           // [18, B, 10, HW]
{
    extern __shared__ char smem[];
    const int tid = threadIdx.x;

    // ---- stage permuted, swizzled bf16 weights (once per block) ----
    for (int idx = tid; idx < 6 * 30 * 257; idx += 256) {
        const int n    = idx / 7710;           // 30*257
        const int rem  = idx - n * 7710;
        const int orow = rem / 257;
        const int c    = rem - orow * 257;
        const int g    = orow / 10;            // 0=i,1=o,2=g in reference order
        const int q    = orow - g * 10;
        const int slot = (g == 0) ? 0 : (g == 1 ? 2 : 1);   // (i,g,o,pad)
        const int t    = n * 10 + q;
        const float v  = W_leaf[idx];
        if (c == 256) {
            ((float*)(smem + kSegOff))[t * 4 + slot] = v;
        } else {
            const int row  = t * 4 + slot;
            const int byte = row * 512 + ((2 * c) ^ ((row & 7) << 4));
            *(unsigned short*)(smem + byte) = bf16b(v);
        }
    }
    // zero the pad rows (keeps MFMA inputs clean)
    for (int i = tid; i < 60 * 128; i += 256) {
        const int t = i >> 7, d = i & 127;
        *(unsigned*)(smem + (t * 4 + 3) * 512 + d * 4) = 0u;
    }
    if (tid < 60) ((float*)(smem + kSegOff))[tid * 4 + 3] = 0.f;
    __syncthreads();

    const int w  = tid >> 6;
    const int ln = tid & 63;
    const int lr = ln & 15;       // A row / B col / D col
    const int lg = ln >> 4;       // k-group / D row-group

    #pragma unroll 1
    for (int r = 0; r < 4; ++r) {
        const int tix  = blockIdx.x * 4 + r;      // 1024 px-tiles of 128 px
        const int b    = tix >> 7;
        const int hw0  = (tix & 127) * 128;
        const int col0 = hw0 + w * 32 + lr;       // this lane's first pixel
        const float* pf = p_fea + b * kCH * kHW;

        f32x4 acc[kMT][2];
        #pragma unroll
        for (int m = 0; m < kMT; ++m) {
            #pragma unroll
            for (int ct = 0; ct < 2; ++ct) {
                acc[m][ct][0] = 0.f; acc[m][ct][1] = 0.f;
                acc[m][ct][2] = 0.f; acc[m][ct][3] = 0.f;
            }
        }

        const float* bbase = pf + lg * 8 * kHW + col0;
        bf16x8 b0 = load_bfrag(bbase);
        bf16x8 b1 = load_bfrag(bbase + 16);

        #pragma unroll
        for (int ks = 0; ks < 8; ++ks) {
            bf16x8 n0, n1;
            if (ks < 7) {                          // prefetch next K-step's B
                const float* nb = bbase + (ks + 1) * 32 * kHW;
                n0 = load_bfrag(nb);
                n1 = load_bfrag(nb + 16);
            }
            const int kb = (ks * 32 + lg * 8) * 2; // 16B-aligned byte offset in a row
            #pragma unroll
            for (int m = 0; m < kMT; ++m) {
                const int row = m * 16 + lr;
                const bf16x8 a = *(const bf16x8*)(
                    smem + row * 512 + (kb ^ ((row & 7) << 4)));
                acc[m][0] = __builtin_amdgcn_mfma_f32_16x16x32_bf16(a, b0, acc[m][0], 0, 0, 0);
                acc[m][1] = __builtin_amdgcn_mfma_f32_16x16x32_bf16(a, b1, acc[m][1], 0, 0, 0);
            }
            b0 = n0; b1 = n1;
        }

        // ---- epilogue: seg channel + gates + store h,c ----
        #pragma unroll
        for (int m = 0; m < kMT; ++m) {
            const int t = m * 4 + lg;             // triple owned by this lane
            const int n = t / 10, q = t - n * 10;
            const float4 sw = *(const float4*)(smem + kSegOff + t * 16);
            const float* sp = seg_p + (b * 7 + n + 1) * kHW;
            float* oh = out + ((n * kB + b) * kHID + q) * kHW;
            float* oc = out + (((9 + n) * kB + b) * kHID + q) * kHW;
            #pragma unroll
            for (int ct = 0; ct < 2; ++ct) {
                const int px = col0 + ct * 16;
                const float sg = sp[px];
                const float ci = acc[m][ct][0] + sw.x * sg;
                const float cg = acc[m][ct][1] + sw.y * sg;
                const float co = acc[m][ct][2] + sw.z * sg;
                const float c  = sigm(ci) * tanh_(cg);
                const float h  = sigm(co) * tanh_(c);
                oh[px] = h;
                oc[px] = c;
            }
        }
    }
}

// 10-row x 8-channel accumulate helper (weights have row stride `rs`)
#define ACC8(accArr, Wbase, rs, rowoff)                                          \
    _Pragma("unroll")                                                            \
    for (int q = 0; q < 10; ++q) {                                               \
        float a_ = accArr[q];                                                    \
        _Pragma("unroll")                                                        \
        for (int j = 0; j < 8; ++j)                                              \
            a_ = fmaf((Wbase)[((rowoff) + q) * (rs) + cbase + j], xcur[j], a_);  \
        accArr[q] = a_;                                                          \
    }

// ---------------- Kernel 2: up + low tree cells (unchanged) ----------------
__global__ __launch_bounds__(256) void k_uplow(
    const float* __restrict__ h_fea,   // [B, CH, HW]
    const float* __restrict__ seg_h,   // [B, 3, HW]
    const float* __restrict__ W_up,    // [30, 267]
    const float* __restrict__ Wf_up,   // [10, 267]
    const float* __restrict__ W_low,   // [30, 267]
    const float* __restrict__ Wf_low,  // [10, 267]
    float* __restrict__ out)
{
    const int t  = blockIdx.x * 256 + threadIdx.x;   // 0 .. B*HW-1
    const int b  = t >> 14;
    const int hw = t & (kHW - 1);
    const float* hf = h_fea + b * kCH * kHW + hw;

    float aUi[10], aUg[10], fU[10];
    float aLi[10], aLo[10], aLg[10], fL[10];
    #pragma unroll
    for (int q = 0; q < 10; ++q) {
        aUi[q] = aUg[q] = fU[q] = 0.f;
        aLi[q] = aLo[q] = aLg[q] = fL[q] = 0.f;
    }

    float xa8[8], xb8[8];
    #pragma unroll
    for (int j = 0; j < 8; ++j) xa8[j] = hf[j * kHW];

    #pragma unroll 1
    for (int c0 = 0; c0 < kCH; c0 += 16) {
        #pragma unroll
        for (int j = 0; j < 8; ++j) xb8[j] = hf[(c0 + 8 + j) * kHW];
        {
            const float* xcur = xa8; const int cbase = c0;
            ACC8(aUi, W_up, 267, 0)  ACC8(aUg, W_up, 267, 20)  ACC8(fU, Wf_up, 267, 0)
            ACC8(aLi, W_low, 267, 0) ACC8(aLo, W_low, 267, 10) ACC8(aLg, W_low, 267, 20)
            ACC8(fL, Wf_low, 267, 0)
        }
        if (c0 + 16 < kCH) {
            #pragma unroll
            for (int j = 0; j < 8; ++j) xa8[j] = hf[(c0 + 16 + j) * kHW];
        }
        {
            const float* xcur = xb8; const int cbase = c0 + 8;
            ACC8(aUi, W_up, 267, 0)  ACC8(aUg, W_up, 267, 20)  ACC8(fU, Wf_up, 267, 0)
            ACC8(aLi, W_low, 267, 0) ACC8(aLo, W_low, 267, 10) ACC8(aLg, W_low, 267, 20)
            ACC8(fL, Wf_low, 267, 0)
        }
    }

    const float sU = seg_h[(b * 3 + 1) * kHW + hw];
    const float sL = seg_h[(b * 3 + 2) * kHW + hw];
    #pragma unroll
    for (int q = 0; q < 10; ++q) {
        aUi[q] = fmaf(W_up[q * 267 + 256], sU, aUi[q]);
        aUg[q] = fmaf(W_up[(20 + q) * 267 + 256], sU, aUg[q]);
        fU[q]  = fmaf(Wf_up[q * 267 + 256], sU, fU[q]);
        aLi[q] = fmaf(W_low[q * 267 + 256], sL, aLi[q]);
        aLo[q] = fmaf(W_low[(10 + q) * 267 + 256], sL, aLo[q]);
        aLg[q] = fmaf(W_low[(20 + q) * 267 + 256], sL, aLg[q]);
        fL[q]  = fmaf(Wf_low[q * 267 + 256], sL, fL[q]);
    }

    float hsU[10], csU[10], hsL[10], csL[10];
    #pragma unroll
    for (int q = 0; q < 10; ++q) { hsU[q] = csU[q] = hsL[q] = csL[q] = 0.f; }

    #pragma unroll 1
    for (int n = 0; n < 4; ++n) {
        float hc[10], cv[10];
        #pragma unroll
        for (int q = 0; q < 10; ++q) hc[q] = out[((n * kB + b) * kHID + q) * kHW + hw];
        #pragma unroll
        for (int q = 0; q < 10; ++q) cv[q] = out[(((9 + n) * kB + b) * kHID + q) * kHW + hw];
        #pragma unroll
        for (int q = 0; q < 10; ++q) hsU[q] += hc[q];
        #pragma unroll
        for (int q = 0; q < 10; ++q) {
            float fh = fU[q];
            #pragma unroll
            for (int j = 0; j < 10; ++j) fh = fmaf(Wf_up[q * 267 + 257 + j], hc[j], fh);
            csU[q] = fmaf(sigm(fh), cv[q], csU[q]);
        }
    }
    #pragma unroll 1
    for (int n = 4; n < 6; ++n) {
        float hc[10], cv[10];
        #pragma unroll
        for (int q = 0; q < 10; ++q) hc[q] = out[((n * kB + b) * kHID + q) * kHW + hw];
        #pragma unroll
        for (int q = 0; q < 10; ++q) cv[q] = out[(((9 + n) * kB + b) * kHID + q) * kHW + hw];
        #pragma unroll
        for (int q = 0; q < 10; ++q) hsL[q] += hc[q];
        #pragma unroll
        for (int q = 0; q < 10; ++q) {
            float fh = fL[q];
            #pragma unroll
            for (int j = 0; j < 10; ++j) fh = fmaf(Wf_low[q * 267 + 257 + j], hc[j], fh);
            csL[q] = fmaf(sigm(fh), cv[q], csL[q]);
        }
    }

    #pragma unroll
    for (int q = 0; q < 10; ++q) {
        float ai = aUi[q], ag = aUg[q];
        #pragma unroll
        for (int j = 0; j < 10; ++j) {
            ai = fmaf(W_up[q * 267 + 257 + j], hsU[j], ai);
            ag = fmaf(W_up[(20 + q) * 267 + 257 + j], hsU[j], ag);
        }
        aUi[q] = ai; aUg[q] = ag;
    }
    #pragma unroll
    for (int q = 0; q < 10; ++q) {
        float ai = aLi[q], ao = aLo[q], ag = aLg[q];
        #pragma unroll
        for (int j = 0; j < 10; ++j) {
            ai = fmaf(W_low[q * 267 + 257 + j], hsL[j], ai);
            ao = fmaf(W_low[(10 + q) * 267 + 257 + j], hsL[j], ao);
            ag = fmaf(W_low[(20 + q) * 267 + 257 + j], hsL[j], ag);
        }
        aLi[q] = ai; aLo[q] = ao; aLg[q] = ag;
    }

    #pragma unroll
    for (int q = 0; q < 10; ++q) {
        out[((15 * kB + b) * kHID + q) * kHW + hw] =
            sigm(aUi[q]) * tanh_(aUg[q]) + csU[q];
    }
    #pragma unroll
    for (int q = 0; q < 10; ++q) {
        const float lcv = sigm(aLi[q]) * tanh_(aLg[q]) + csL[q];
        const float lhv = sigm(aLo[q]) * tanh_(lcv);
        out[((6 * kB + b) * kHID + q) * kHW + hw]  = lhv;
        out[((7 * kB + b) * kHID + q) * kHW + hw]  = lhv;
        out[((16 * kB + b) * kHID + q) * kHW + hw] = lcv;
    }
}

// ---------------- Kernel 3: full body cell (unchanged) ----------------
__global__ __launch_bounds__(256) void k_full(
    const float* __restrict__ f_fea,    // [B, CH, HW]
    const float* __restrict__ seg_f,    // [B, 2, HW]
    const float* __restrict__ W_full,   // [30, 267]
    const float* __restrict__ Wf_full,  // [10, 267]
    float* __restrict__ out)
{
    const int t  = blockIdx.x * 256 + threadIdx.x;
    const int b  = t >> 14;
    const int hw = t & (kHW - 1);
    const float* ff = f_fea + b * kCH * kHW + hw;

    float ai[10], ao[10], ag[10], fx[10];
    #pragma unroll
    for (int q = 0; q < 10; ++q) { ai[q] = ao[q] = ag[q] = fx[q] = 0.f; }

    float xa8[8], xb8[8];
    #pragma unroll
    for (int j = 0; j < 8; ++j) xa8[j] = ff[j * kHW];

    #pragma unroll 1
    for (int c0 = 0; c0 < kCH; c0 += 16) {
        #pragma unroll
        for (int j = 0; j < 8; ++j) xb8[j] = ff[(c0 + 8 + j) * kHW];
        {
            const float* xcur = xa8; const int cbase = c0;
            ACC8(ai, W_full, 267, 0) ACC8(ao, W_full, 267, 10)
            ACC8(ag, W_full, 267, 20) ACC8(fx, Wf_full, 267, 0)
        }
        if (c0 + 16 < kCH) {
            #pragma unroll
            for (int j = 0; j < 8; ++j) xa8[j] = ff[(c0 + 16 + j) * kHW];
        }
        {
            const float* xcur = xb8; const int cbase = c0 + 8;
            ACC8(ai, W_full, 267, 0) ACC8(ao, W_full, 267, 10)
            ACC8(ag, W_full, 267, 20) ACC8(fx, Wf_full, 267, 0)
        }
    }

    const float sF = seg_f[(b * 2 + 1) * kHW + hw];
    #pragma unroll
    for (int q = 0; q < 10; ++q) {
        ai[q] = fmaf(W_full[q * 267 + 256], sF, ai[q]);
        ao[q] = fmaf(W_full[(10 + q) * 267 + 256], sF, ao[q]);
        ag[q] = fmaf(W_full[(20 + q) * 267 + 256], sF, ag[q]);
        fx[q] = fmaf(Wf_full[q * 267 + 256], sF, fx[q]);
    }

    float lh[10], uc[10], lc[10];
    #pragma unroll
    for (int q = 0; q < 10; ++q) lh[q] = out[((6 * kB + b) * kHID + q) * kHW + hw];
    #pragma unroll
    for (int q = 0; q < 10; ++q) uc[q] = out[((15 * kB + b) * kHID + q) * kHW + hw];
    #pragma unroll
    for (int q = 0; q < 10; ++q) lc[q] = out[((16 * kB + b) * kHID + q) * kHW + hw];

    #pragma unroll
    for (int q = 0; q < 10; ++q) {
        float a0 = ai[q], a1 = ao[q], a2 = ag[q], fh = fx[q];
        #pragma unroll
        for (int j = 0; j < 10; ++j) {
            const float h2 = 2.0f * lh[j];
            a0 = fmaf(W_full[q * 267 + 257 + j], h2, a0);
            a1 = fmaf(W_full[(10 + q) * 267 + 257 + j], h2, a1);
            a2 = fmaf(W_full[(20 + q) * 267 + 257 + j], h2, a2);
            fh = fmaf(Wf_full[q * 267 + 257 + j], lh[j], fh);
        }
        const float f  = sigm(fh);
        const float cf = sigm(a0) * tanh_(a2) + f * (uc[q] + lc[q]);
        const float hv = sigm(a1) * tanh_(cf);
        out[((8 * kB + b) * kHID + q) * kHW + hw]  = hv;
        out[((17 * kB + b) * kHID + q) * kHW + hw] = cf;
    }
}

}  // namespace

extern "C" void kernel_launch(void* const* d_in, const int* in_sizes, int n_in,
                              void* d_out, int out_size, void* d_ws, size_t ws_size,
                              hipStream_t stream) {
    const float* seg_p   = (const float*)d_in[0];
    const float* seg_h   = (const float*)d_in[1];
    const float* seg_f   = (const float*)d_in[2];
    const float* p_fea   = (const float*)d_in[3];
    const float* h_fea   = (const float*)d_in[4];
    const float* f_fea   = (const float*)d_in[5];
    const float* W_leaf  = (const float*)d_in[6];
    const float* W_up    = (const float*)d_in[7];
    const float* Wf_up   = (const float*)d_in[8];
    const float* W_low   = (const float*)d_in[9];
    const float* Wf_low  = (const float*)d_in[10];
    const float* W_full  = (const float*)d_in[11];
    const float* Wf_full = (const float*)d_in[12];
    float* out = (float*)d_out;

    // >64 KB dynamic LDS opt-in (gfx950 supports up to 160 KB/workgroup)
    (void)hipFuncSetAttribute(reinterpret_cast<const void*>(k_leaf_mfma),
                              hipFuncAttributeMaxDynamicSharedMemorySize, kLdsBytes);

    hipLaunchKernelGGL(k_leaf_mfma, dim3(256), dim3(256), kLdsBytes, stream,
                       p_fea, seg_p, W_leaf, out);
    hipLaunchKernelGGL(k_uplow, dim3(kB * kHW / 256), dim3(256), 0, stream,
                       h_fea, seg_h, W_up, Wf_up, W_low, Wf_low, out);
    hipLaunchKernelGGL(k_full, dim3(kB * kHW / 256), dim3(256), 0, stream,
                       f_fea, seg_f, W_full, Wf_full, out);
}

// Round 3
// 602.636 us; speedup vs baseline: 2.7318x; 1.6897x over previous
//
#include <hip/hip_runtime.h>

namespace {

constexpr int kHW  = 128 * 128;
constexpr int kCH  = 256;
constexpr int kHID = 10;
constexpr int kB   = 8;

typedef __attribute__((ext_vector_type(8))) short bf16x8;
typedef __attribute__((ext_vector_type(4))) float f32x4;

constexpr int kMT       = 15;          // leaf M-tiles (240 rows)
constexpr int kSegOff   = 240 * 512;   // leaf seg-table offset
constexpr int kLdsBytes = kSegOff + 60 * 4 * 4;

// uplow: 80 rows (20 quads) + side table [80][11] fp32
constexpr int kSideOffU  = 80 * 512;
constexpr int kLdsBytesU = kSideOffU + 80 * 11 * 4;
// full: 48 rows (12 quads, 2 pad) + side table [48][11] fp32
constexpr int kSideOffF  = 48 * 512;
constexpr int kLdsBytesF = kSideOffF + 48 * 11 * 4;

__device__ __forceinline__ float sigm(float x) {
    return __builtin_amdgcn_rcpf(1.0f + __expf(-x));
}
__device__ __forceinline__ float tanh_(float x) {
    return 1.0f - 2.0f * __builtin_amdgcn_rcpf(__expf(2.0f * x) + 1.0f);
}
__device__ __forceinline__ unsigned short bf16b(float f) {
    unsigned u = __float_as_uint(f);
    return (unsigned short)((u + 0x7FFFu + ((u >> 16) & 1u)) >> 16);  // RNE-ish
}
__device__ __forceinline__ bf16x8 load_bfrag(const float* __restrict__ base) {
    float v[8];
    #pragma unroll
    for (int j = 0; j < 8; ++j) v[j] = base[j * kHW];
    bf16x8 r;
    #pragma unroll
    for (int j = 0; j < 8; ++j) r[j] = (short)bf16b(v[j]);
    return r;
}

// ---------------- Kernel 1 (MFMA): six leaf ConvLSTM cells ----------------
// GEMM: Wp[240,256](bf16, LDS, swizzled) x X[256, px](p_fea fp32->bf16).
// Row permutation: triple t = leaf*10+q, rows t*4+{0:i,1:g,2:o,3:pad}.
// C-layout (m89): col=lane&15, row=(lane>>4)*4+reg -> lane's 4 regs = one triple.
__global__ __launch_bounds__(256, 1) void k_leaf_mfma(
    const float* __restrict__ p_fea,   // [B, CH, HW]
    const float* __restrict__ seg_p,   // [B, 7, HW]
    const float* __restrict__ W_leaf,  // [6, 30, 257]
    float* __restrict__ out)           // [18, B, 10, HW]
{
    extern __shared__ char smem[];
    const int tid = threadIdx.x;

    for (int idx = tid; idx < 6 * 30 * 257; idx += 256) {
        const int n    = idx / 7710;           // 30*257
        const int rem  = idx - n * 7710;
        const int orow = rem / 257;
        const int c    = rem - orow * 257;
        const int g    = orow / 10;            // 0=i,1=o,2=g in reference order
        const int q    = orow - g * 10;
        const int slot = (g == 0) ? 0 : (g == 1 ? 2 : 1);   // (i,g,o,pad)
        const int t    = n * 10 + q;
        const float v  = W_leaf[idx];
        if (c == 256) {
            ((float*)(smem + kSegOff))[t * 4 + slot] = v;
        } else {
            const int row  = t * 4 + slot;
            const int byte = row * 512 + ((2 * c) ^ ((row & 7) << 4));
            *(unsigned short*)(smem + byte) = bf16b(v);
        }
    }
    for (int i = tid; i < 60 * 128; i += 256) {
        const int t = i >> 7, d = i & 127;
        *(unsigned*)(smem + (t * 4 + 3) * 512 + d * 4) = 0u;
    }
    if (tid < 60) ((float*)(smem + kSegOff))[tid * 4 + 3] = 0.f;
    __syncthreads();

    const int w  = tid >> 6;
    const int ln = tid & 63;
    const int lr = ln & 15;
    const int lg = ln >> 4;

    #pragma unroll 1
    for (int r = 0; r < 4; ++r) {
        const int tix  = blockIdx.x * 4 + r;
        const int b    = tix >> 7;
        const int hw0  = (tix & 127) * 128;
        const int col0 = hw0 + w * 32 + lr;
        const float* pf = p_fea + b * kCH * kHW;

        f32x4 acc[kMT][2];
        #pragma unroll
        for (int m = 0; m < kMT; ++m)
            #pragma unroll
            for (int ct = 0; ct < 2; ++ct) {
                acc[m][ct][0] = 0.f; acc[m][ct][1] = 0.f;
                acc[m][ct][2] = 0.f; acc[m][ct][3] = 0.f;
            }

        const float* bbase = pf + lg * 8 * kHW + col0;
        bf16x8 b0 = load_bfrag(bbase);
        bf16x8 b1 = load_bfrag(bbase + 16);

        #pragma unroll
        for (int ks = 0; ks < 8; ++ks) {
            bf16x8 n0, n1;
            if (ks < 7) {
                const float* nb = bbase + (ks + 1) * 32 * kHW;
                n0 = load_bfrag(nb);
                n1 = load_bfrag(nb + 16);
            }
            const int kb = (ks * 32 + lg * 8) * 2;
            #pragma unroll
            for (int m = 0; m < kMT; ++m) {
                const int row = m * 16 + lr;
                const bf16x8 a = *(const bf16x8*)(
                    smem + row * 512 + (kb ^ ((row & 7) << 4)));
                acc[m][0] = __builtin_amdgcn_mfma_f32_16x16x32_bf16(a, b0, acc[m][0], 0, 0, 0);
                acc[m][1] = __builtin_amdgcn_mfma_f32_16x16x32_bf16(a, b1, acc[m][1], 0, 0, 0);
            }
            b0 = n0; b1 = n1;
        }

        #pragma unroll
        for (int m = 0; m < kMT; ++m) {
            const int t = m * 4 + lg;
            const int n = t / 10, q = t - n * 10;
            const float4 sw = *(const float4*)(smem + kSegOff + t * 16);
            const float* sp = seg_p + (b * 7 + n + 1) * kHW;
            float* oh = out + ((n * kB + b) * kHID + q) * kHW;
            float* oc = out + (((9 + n) * kB + b) * kHID + q) * kHW;
            #pragma unroll
            for (int ct = 0; ct < 2; ++ct) {
                const int px = col0 + ct * 16;
                const float sg = sp[px];
                const float ci = acc[m][ct][0] + sw.x * sg;
                const float cg = acc[m][ct][1] + sw.y * sg;
                const float co = acc[m][ct][2] + sw.z * sg;
                const float c  = sigm(ci) * tanh_(cg);
                const float h  = sigm(co) * tanh_(c);
                oh[px] = h;
                oc[px] = c;
            }
        }
    }
}

// ---------------- Kernel 2 (MFMA): up + low tree cells ----------------
// Quads t=0..9 (up, q=t): rows 4t+{0:i, 1:g, 2:f, 3:pad}
// Quads t=10..19 (low, q=t-10): rows 4t+{0:i, 1:g, 2:o, 3:f}
// up's o-gate is dead (up_h unused) -> skipped entirely.
__global__ __launch_bounds__(256, 2) void k_uplow_mfma(
    const float* __restrict__ h_fea,   // [B, CH, HW]
    const float* __restrict__ seg_h,   // [B, 3, HW]
    const float* __restrict__ W_up,    // [30, 267]
    const float* __restrict__ Wf_up,   // [10, 267]
    const float* __restrict__ W_low,   // [30, 267]
    const float* __restrict__ Wf_low,  // [10, 267]
    float* __restrict__ out)
{
    extern __shared__ char smem[];
    const int tid = threadIdx.x;

    for (int idx = tid; idx < 80 * 267; idx += 256) {
        const int row = idx / 267;
        const int c   = idx - row * 267;
        const int t = row >> 2, slot = row & 3;
        float v = 0.f;
        if (t < 10) {
            const int q = t;
            if      (slot == 0) v = W_up[q * 267 + c];
            else if (slot == 1) v = W_up[(20 + q) * 267 + c];
            else if (slot == 2) v = Wf_up[q * 267 + c];
        } else {
            const int q = t - 10;
            if      (slot == 0) v = W_low[q * 267 + c];
            else if (slot == 1) v = W_low[(20 + q) * 267 + c];
            else if (slot == 2) v = W_low[(10 + q) * 267 + c];
            else                v = Wf_low[q * 267 + c];
        }
        if (c < 256) {
            const int byte = row * 512 + ((2 * c) ^ ((row & 7) << 4));
            *(unsigned short*)(smem + byte) = bf16b(v);
        } else {
            ((float*)(smem + kSideOffU))[row * 11 + (c - 256)] = v;
        }
    }
    __syncthreads();

    const int w  = tid >> 6;
    const int ln = tid & 63;
    const int lr = ln & 15;
    const int lg = ln >> 4;
    const float* sideT = (const float*)(smem + kSideOffU);

    #pragma unroll 1
    for (int tix = blockIdx.x; tix < 1024; tix += gridDim.x) {
        const int b    = tix >> 7;
        const int hw0  = (tix & 127) * 128;
        const int col0 = hw0 + w * 32 + lr;
        const float* hf = h_fea + b * kCH * kHW;

        f32x4 acc[5][2];
        #pragma unroll
        for (int m = 0; m < 5; ++m)
            #pragma unroll
            for (int ct = 0; ct < 2; ++ct) {
                acc[m][ct][0] = 0.f; acc[m][ct][1] = 0.f;
                acc[m][ct][2] = 0.f; acc[m][ct][3] = 0.f;
            }

        const float* bbase = hf + lg * 8 * kHW + col0;
        bf16x8 b0 = load_bfrag(bbase);
        bf16x8 b1 = load_bfrag(bbase + 16);

        #pragma unroll
        for (int ks = 0; ks < 8; ++ks) {
            bf16x8 n0, n1;
            if (ks < 7) {
                const float* nb = bbase + (ks + 1) * 32 * kHW;
                n0 = load_bfrag(nb);
                n1 = load_bfrag(nb + 16);
            }
            const int kb = (ks * 32 + lg * 8) * 2;
            #pragma unroll
            for (int m = 0; m < 5; ++m) {
                const int row = m * 16 + lr;
                const bf16x8 a = *(const bf16x8*)(
                    smem + row * 512 + (kb ^ ((row & 7) << 4)));
                acc[m][0] = __builtin_amdgcn_mfma_f32_16x16x32_bf16(a, b0, acc[m][0], 0, 0, 0);
                acc[m][1] = __builtin_amdgcn_mfma_f32_16x16x32_bf16(a, b1, acc[m][1], 0, 0, 0);
            }
            b0 = n0; b1 = n1;
        }

        #pragma unroll 1
        for (int ct = 0; ct < 2; ++ct) {
            const int px = col0 + ct * 16;
            const float sU = seg_h[(b * 3 + 1) * kHW + px];
            const float sL = seg_h[(b * 3 + 2) * kHW + px];

            // per-quad pre-gates with seg contribution
            float pi[5], pg[5], po[5], pf_[5], cs[5];
            #pragma unroll
            for (int m = 0; m < 5; ++m) {
                const int t = m * 4 + lg;
                const float sv = (t < 10) ? sU : sL;
                pi[m] = acc[m][ct][0] + sideT[(t * 4 + 0) * 11] * sv;
                pg[m] = acc[m][ct][1] + sideT[(t * 4 + 1) * 11] * sv;
                if (t < 10) {
                    pf_[m] = acc[m][ct][2] + sideT[(t * 4 + 2) * 11] * sv;
                    po[m]  = 0.f;
                } else {
                    po[m]  = acc[m][ct][2] + sideT[(t * 4 + 2) * 11] * sv;
                    pf_[m] = acc[m][ct][3] + sideT[(t * 4 + 3) * 11] * sv;
                }
                cs[m] = 0.f;
            }

            float hsU[10], hsL[10];
            #pragma unroll
            for (int j = 0; j < 10; ++j) { hsU[j] = 0.f; hsL[j] = 0.f; }

            // children 0..3 feed the up cell
            #pragma unroll 1
            for (int n = 0; n < 4; ++n) {
                float hc[10];
                #pragma unroll
                for (int j = 0; j < 10; ++j)
                    hc[j] = out[((n * kB + b) * kHID + j) * kHW + px];
                #pragma unroll
                for (int j = 0; j < 10; ++j) hsU[j] += hc[j];
                #pragma unroll
                for (int m = 0; m < 5; ++m) {
                    const int t = m * 4 + lg;
                    if (t < 10) {
                        float fh = pf_[m];
                        #pragma unroll
                        for (int j = 0; j < 10; ++j)
                            fh = fmaf(sideT[(t * 4 + 2) * 11 + 1 + j], hc[j], fh);
                        const float cv = out[(((9 + n) * kB + b) * kHID + t) * kHW + px];
                        cs[m] = fmaf(sigm(fh), cv, cs[m]);
                    }
                }
            }
            // children 4..5 feed the low cell
            #pragma unroll 1
            for (int n = 4; n < 6; ++n) {
                float hc[10];
                #pragma unroll
                for (int j = 0; j < 10; ++j)
                    hc[j] = out[((n * kB + b) * kHID + j) * kHW + px];
                #pragma unroll
                for (int j = 0; j < 10; ++j) hsL[j] += hc[j];
                #pragma unroll
                for (int m = 0; m < 5; ++m) {
                    const int t = m * 4 + lg;
                    if (t >= 10) {
                        float fh = pf_[m];
                        #pragma unroll
                        for (int j = 0; j < 10; ++j)
                            fh = fmaf(sideT[(t * 4 + 3) * 11 + 1 + j], hc[j], fh);
                        const float cv = out[(((9 + n) * kB + b) * kHID + (t - 10)) * kHW + px];
                        cs[m] = fmaf(sigm(fh), cv, cs[m]);
                    }
                }
            }

            // hidden-sum coupling + gates + stores
            #pragma unroll
            for (int m = 0; m < 5; ++m) {
                const int t = m * 4 + lg;
                if (t < 10) {
                    float ai = pi[m], ag = pg[m];
                    #pragma unroll
                    for (int j = 0; j < 10; ++j) {
                        ai = fmaf(sideT[(t * 4 + 0) * 11 + 1 + j], hsU[j], ai);
                        ag = fmaf(sideT[(t * 4 + 1) * 11 + 1 + j], hsU[j], ag);
                    }
                    out[((15 * kB + b) * kHID + t) * kHW + px] =
                        sigm(ai) * tanh_(ag) + cs[m];
                } else {
                    const int q = t - 10;
                    float ai = pi[m], ag = pg[m], ao = po[m];
                    #pragma unroll
                    for (int j = 0; j < 10; ++j) {
                        ai = fmaf(sideT[(t * 4 + 0) * 11 + 1 + j], hsL[j], ai);
                        ag = fmaf(sideT[(t * 4 + 1) * 11 + 1 + j], hsL[j], ag);
                        ao = fmaf(sideT[(t * 4 + 2) * 11 + 1 + j], hsL[j], ao);
                    }
                    const float lcv = sigm(ai) * tanh_(ag) + cs[m];
                    const float lhv = sigm(ao) * tanh_(lcv);
                    out[((6 * kB + b) * kHID + q) * kHW + px]  = lhv;
                    out[((7 * kB + b) * kHID + q) * kHW + px]  = lhv;
                    out[((16 * kB + b) * kHID + q) * kHW + px] = lcv;
                }
            }
        }
    }
}

// ---------------- Kernel 3 (MFMA): full body cell ----------------
// Quads t=0..9 (q=t): rows 4t+{0:i, 1:g, 2:o, 3:f}; t=10,11 pad.
// h_sum = 2*low_h -> fold the 2 into staged coupling weights for i,g,o.
__global__ __launch_bounds__(256, 2) void k_full_mfma(
    const float* __restrict__ f_fea,    // [B, CH, HW]
    const float* __restrict__ seg_f,    // [B, 2, HW]
    const float* __restrict__ W_full,   // [30, 267]
    const float* __restrict__ Wf_full,  // [10, 267]
    float* __restrict__ out)
{
    extern __shared__ char smem[];
    const int tid = threadIdx.x;

    for (int idx = tid; idx < 48 * 267; idx += 256) {
        const int row = idx / 267;
        const int c   = idx - row * 267;
        const int t = row >> 2, slot = row & 3;
        float v = 0.f;
        if (t < 10) {
            const int q = t;
            if      (slot == 0) v = W_full[q * 267 + c];
            else if (slot == 1) v = W_full[(20 + q) * 267 + c];
            else if (slot == 2) v = W_full[(10 + q) * 267 + c];
            else                v = Wf_full[q * 267 + c];
            if (c >= 257 && slot < 3) v *= 2.0f;   // h_sum = 2*low_h
        }
        if (c < 256) {
            const int byte = row * 512 + ((2 * c) ^ ((row & 7) << 4));
            *(unsigned short*)(smem + byte) = bf16b(v);
        } else {
            ((float*)(smem + kSideOffF))[row * 11 + (c - 256)] = v;
        }
    }
    __syncthreads();

    const int w  = tid >> 6;
    const int ln = tid & 63;
    const int lr = ln & 15;
    const int lg = ln >> 4;
    const float* sideT = (const float*)(smem + kSideOffF);

    #pragma unroll 1
    for (int tix = blockIdx.x; tix < 1024; tix += gridDim.x) {
        const int b    = tix >> 7;
        const int hw0  = (tix & 127) * 128;
        const int col0 = hw0 + w * 32 + lr;
        const float* ff = f_fea + b * kCH * kHW;

        f32x4 acc[3][2];
        #pragma unroll
        for (int m = 0; m < 3; ++m)
            #pragma unroll
            for (int ct = 0; ct < 2; ++ct) {
                acc[m][ct][0] = 0.f; acc[m][ct][1] = 0.f;
                acc[m][ct][2] = 0.f; acc[m][ct][3] = 0.f;
            }

        const float* bbase = ff + lg * 8 * kHW + col0;
        bf16x8 b0 = load_bfrag(bbase);
        bf16x8 b1 = load_bfrag(bbase + 16);

        #pragma unroll
        for (int ks = 0; ks < 8; ++ks) {
            bf16x8 n0, n1;
            if (ks < 7) {
                const float* nb = bbase + (ks + 1) * 32 * kHW;
                n0 = load_bfrag(nb);
                n1 = load_bfrag(nb + 16);
            }
            const int kb = (ks * 32 + lg * 8) * 2;
            #pragma unroll
            for (int m = 0; m < 3; ++m) {
                const int row = m * 16 + lr;
                const bf16x8 a = *(const bf16x8*)(
                    smem + row * 512 + (kb ^ ((row & 7) << 4)));
                acc[m][0] = __builtin_amdgcn_mfma_f32_16x16x32_bf16(a, b0, acc[m][0], 0, 0, 0);
                acc[m][1] = __builtin_amdgcn_mfma_f32_16x16x32_bf16(a, b1, acc[m][1], 0, 0, 0);
            }
            b0 = n0; b1 = n1;
        }

        #pragma unroll 1
        for (int ct = 0; ct < 2; ++ct) {
            const int px = col0 + ct * 16;
            const float sF = seg_f[(b * 2 + 1) * kHW + px];
            float lh[10];
            #pragma unroll
            for (int j = 0; j < 10; ++j)
                lh[j] = out[((6 * kB + b) * kHID + j) * kHW + px];

            #pragma unroll
            for (int m = 0; m < 3; ++m) {
                const int t = m * 4 + lg;
                if (t < 10) {
                    float ai = acc[m][ct][0] + sideT[(t * 4 + 0) * 11] * sF;
                    float ag = acc[m][ct][1] + sideT[(t * 4 + 1) * 11] * sF;
                    float ao = acc[m][ct][2] + sideT[(t * 4 + 2) * 11] * sF;
                    float fh = acc[m][ct][3] + sideT[(t * 4 + 3) * 11] * sF;
                    #pragma unroll
                    for (int j = 0; j < 10; ++j) {
                        ai = fmaf(sideT[(t * 4 + 0) * 11 + 1 + j], lh[j], ai);
                        ag = fmaf(sideT[(t * 4 + 1) * 11 + 1 + j], lh[j], ag);
                        ao = fmaf(sideT[(t * 4 + 2) * 11 + 1 + j], lh[j], ao);
                        fh = fmaf(sideT[(t * 4 + 3) * 11 + 1 + j], lh[j], fh);
                    }
                    const float uc = out[((15 * kB + b) * kHID + t) * kHW + px];
                    const float lc = out[((16 * kB + b) * kHID + t) * kHW + px];
                    const float cf = sigm(ai) * tanh_(ag) + sigm(fh) * (uc + lc);
                    const float hv = sigm(ao) * tanh_(cf);
                    out[((8 * kB + b) * kHID + t) * kHW + px]  = hv;
                    out[((17 * kB + b) * kHID + t) * kHW + px] = cf;
                }
            }
        }
    }
}

}  // namespace

extern "C" void kernel_launch(void* const* d_in, const int* in_sizes, int n_in,
                              void* d_out, int out_size, void* d_ws, size_t ws_size,
                              hipStream_t stream) {
    const float* seg_p   = (const float*)d_in[0];
    const float* seg_h   = (const float*)d_in[1];
    const float* seg_f   = (const float*)d_in[2];
    const float* p_fea   = (const float*)d_in[3];
    const float* h_fea   = (const float*)d_in[4];
    const float* f_fea   = (const float*)d_in[5];
    const float* W_leaf  = (const float*)d_in[6];
    const float* W_up    = (const float*)d_in[7];
    const float* Wf_up   = (const float*)d_in[8];
    const float* W_low   = (const float*)d_in[9];
    const float* Wf_low  = (const float*)d_in[10];
    const float* W_full  = (const float*)d_in[11];
    const float* Wf_full = (const float*)d_in[12];
    float* out = (float*)d_out;

    (void)hipFuncSetAttribute(reinterpret_cast<const void*>(k_leaf_mfma),
                              hipFuncAttributeMaxDynamicSharedMemorySize, kLdsBytes);

    hipLaunchKernelGGL(k_leaf_mfma, dim3(256), dim3(256), kLdsBytes, stream,
                       p_fea, seg_p, W_leaf, out);
    hipLaunchKernelGGL(k_uplow_mfma, dim3(512), dim3(256), kLdsBytesU, stream,
                       h_fea, seg_h, W_up, Wf_up, W_low, Wf_low, out);
    hipLaunchKernelGGL(k_full_mfma, dim3(1024), dim3(256), kLdsBytesF, stream,
                       f_fea, seg_f, W_full, Wf_full, out);
}